// Round 3
// baseline (93.398 us; speedup 1.0000x reference)
//
#include <hip/hip_runtime.h>
#include <hip/hip_bf16.h>

// ModulatedLinear: B=4, S=4096, IN=OUT=MOD=512
// out[t,o] = demod[t,o] * sum_i W[o,i]*s[t,i]*x[t,i] + bias[o]
//   s[t,i]    = sum_m mod[t,m]*mod_w[i,m] + mod_b[i]
//   demod[t,o]= rsqrt(sum_i (W[o,i]*s[t,i])^2 + 1e-8)
//
// bf16 MFMA pipeline:
//  K0: fp32->bf16 converts (modulation, W, W^2, mod_w)
//  K1: s = modb @ mod_wb^T; LDS-transpose epilogue -> xs=bf16(x*s), ss=bf16(s*s)
//  K2: dual GEMM out1=xs@Wb^T, out2=ss@W2b^T (BM=64,BN=128, 3 blk/CU, XCD swizzle);
//      LDS-transpose epilogue -> float4 stores of out1*rsqrt(out2+eps)+bias

#define T_TOK 16384
#define DIM 512

typedef __attribute__((ext_vector_type(4))) float f32x4;
typedef __attribute__((ext_vector_type(8))) short bf16x8;

static __device__ __forceinline__ unsigned short f2bf(float f) {
    union { float f; unsigned int u; } v; v.f = f;
    unsigned int u = v.u;
    u += 0x7fffu + ((u >> 16) & 1u);   // RNE
    return (unsigned short)(u >> 16);
}
static __device__ __forceinline__ float bf2f(unsigned short h) {
    union { unsigned int u; float f; } v; v.u = ((unsigned int)h) << 16;
    return v.f;
}

// ---------------- K0: converts ----------------
__global__ __launch_bounds__(256) void k0_convert(
    const float* __restrict__ mod, const float* __restrict__ weight,
    const float* __restrict__ mod_w,
    unsigned short* __restrict__ modb, unsigned short* __restrict__ Wb,
    unsigned short* __restrict__ W2b, unsigned short* __restrict__ mwb)
{
    const int NV_MOD = (T_TOK * DIM) / 4;
    const int NV_W   = (DIM * DIM) / 4;
    int idx = blockIdx.x * blockDim.x + threadIdx.x;
    int stride = gridDim.x * blockDim.x;
    for (int i = idx; i < NV_MOD; i += stride) {
        f32x4 v = ((const f32x4*)mod)[i];
        ushort4 o; o.x = f2bf(v[0]); o.y = f2bf(v[1]); o.z = f2bf(v[2]); o.w = f2bf(v[3]);
        ((ushort4*)modb)[i] = o;
    }
    for (int i = idx; i < NV_W; i += stride) {
        f32x4 v = ((const f32x4*)weight)[i];
        ushort4 o;  o.x = f2bf(v[0]); o.y = f2bf(v[1]); o.z = f2bf(v[2]); o.w = f2bf(v[3]);
        ((ushort4*)Wb)[i] = o;
        ushort4 o2; o2.x = f2bf(v[0]*v[0]); o2.y = f2bf(v[1]*v[1]);
                    o2.z = f2bf(v[2]*v[2]); o2.w = f2bf(v[3]*v[3]);
        ((ushort4*)W2b)[i] = o2;
        f32x4 m = ((const f32x4*)mod_w)[i];
        ushort4 o3; o3.x = f2bf(m[0]); o3.y = f2bf(m[1]); o3.z = f2bf(m[2]); o3.w = f2bf(m[3]);
        ((ushort4*)mwb)[i] = o3;
    }
}

// LDS tiles: [rows][64] bf16, physical 16B-slot = logical ^ (row & 7).
// global_load_lds writes wave-uniform-base + lane*16, so the GLOBAL source
// address carries the swizzle (both-sides-or-neither).

// ---------------- K1: s-GEMM + LDS-transpose epilogue ----------------
__global__ __launch_bounds__(256, 4) void k1_style(
    const unsigned short* __restrict__ modb,   // [T][512] bf16
    const unsigned short* __restrict__ mwb,    // [512][512] bf16 (IN x MOD)
    const float* __restrict__ x,               // [T][512] fp32
    const float* __restrict__ mod_b,           // [512]
    unsigned short* __restrict__ xs,           // [T][512] bf16 out
    unsigned short* __restrict__ ss)           // [T][512] bf16 out
{
    __shared__ union {
        struct { unsigned short A[128 * 64]; unsigned short B[128 * 64]; } stg;
        unsigned short str[128 * 144];   // padded s-transpose buffer (36.9KB)
    } u;
    const int tid  = threadIdx.x;
    const int lane = tid & 63;
    const int w    = tid >> 6;
    const int wr   = w >> 1, wc = w & 1;
    // XCD-chunked swizzle: 512 blocks, 64 per XCD; consecutive tiles (same bm,
    // all 4 bn) land on one XCD -> modb rows shared in that XCD's L2.
    const int tile = (blockIdx.x & 7) * 64 + (blockIdx.x >> 3);
    const int bm   = tile >> 2;
    const int bn   = tile & 3;

    const int srow  = lane >> 3;
    const int lslot = (lane & 7) ^ srow;
    const int fr    = lane & 15;
    const int fs    = lane >> 4;

    f32x4 acc[4][4] = {};

    const size_t aBase = (size_t)bm * 128 * DIM;
    const size_t bBase = (size_t)bn * 128 * DIM;

    for (int kb = 0; kb < DIM; kb += 64) {
#pragma unroll
        for (int q = 0; q < 4; ++q) {
            int row = w * 32 + q * 8 + srow;
            const unsigned short* ga = modb + aBase + (size_t)row * DIM + kb + lslot * 8;
            const unsigned short* gb = mwb  + bBase + (size_t)row * DIM + kb + lslot * 8;
            __builtin_amdgcn_global_load_lds(
                (__attribute__((address_space(1))) void*)ga,
                (__attribute__((address_space(3))) void*)(u.stg.A + w * 2048 + q * 512), 16, 0, 0);
            __builtin_amdgcn_global_load_lds(
                (__attribute__((address_space(1))) void*)gb,
                (__attribute__((address_space(3))) void*)(u.stg.B + w * 2048 + q * 512), 16, 0, 0);
        }
        __syncthreads();
#pragma unroll
        for (int kk = 0; kk < 64; kk += 32) {
            bf16x8 af[4], bfv[4];
#pragma unroll
            for (int mi = 0; mi < 4; ++mi) {
                int row = wr * 64 + mi * 16 + fr;
                int ps  = ((kk >> 3) + fs) ^ (fr & 7);
                af[mi] = *(const bf16x8*)(u.stg.A + row * 64 + ps * 8);
            }
#pragma unroll
            for (int ni = 0; ni < 4; ++ni) {
                int row = wc * 64 + ni * 16 + fr;
                int ps  = ((kk >> 3) + fs) ^ (fr & 7);
                bfv[ni] = *(const bf16x8*)(u.stg.B + row * 64 + ps * 8);
            }
#pragma unroll
            for (int mi = 0; mi < 4; ++mi)
#pragma unroll
                for (int ni = 0; ni < 4; ++ni)
                    acc[mi][ni] = __builtin_amdgcn_mfma_f32_16x16x32_bf16(
                        af[mi], bfv[ni], acc[mi][ni], 0, 0, 0);
        }
        __syncthreads();
    }

    // scatter s = acc + mod_b as bf16 into padded LDS [128][144]
#pragma unroll
    for (int ni = 0; ni < 4; ++ni) {
        int col = wc * 64 + ni * 16 + fr;
        float mb = mod_b[bn * 128 + col];
#pragma unroll
        for (int mi = 0; mi < 4; ++mi) {
#pragma unroll
            for (int j = 0; j < 4; ++j) {
                int row = wr * 64 + mi * 16 + fs * 4 + j;
                u.str[row * 144 + col] = f2bf(acc[mi][ni][j] + mb);
            }
        }
    }
    __syncthreads();
    // coalesced: read s rows, load x float4, write xs/ss ushort8
#pragma unroll
    for (int q = 0; q < 8; ++q) {
        int row = w * 32 + q * 4 + (lane >> 4);
        int c8  = (lane & 15) * 8;
        bf16x8 s8 = *(const bf16x8*)(u.str + row * 144 + c8);
        size_t off = ((size_t)bm * 128 + row) * DIM + bn * 128 + c8;
        f32x4 x0 = *(const f32x4*)(x + off);
        f32x4 x1 = *(const f32x4*)(x + off + 4);
        bf16x8 xsv, ssv;
#pragma unroll
        for (int e = 0; e < 8; ++e) {
            float sf = bf2f((unsigned short)s8[e]);
            float xv = (e < 4) ? x0[e] : x1[e - 4];
            xsv[e] = (short)f2bf(xv * sf);
            ssv[e] = (short)f2bf(sf * sf);
        }
        *(bf16x8*)(xs + off) = xsv;
        *(bf16x8*)(ss + off) = ssv;
    }
}

// ---------------- K2: dual GEMM, BM=64 BN=128, 3 blk/CU ----------------
__global__ __launch_bounds__(256, 3) void k2_main(
    const unsigned short* __restrict__ xs,   // [T][512] bf16
    const unsigned short* __restrict__ ss,   // [T][512] bf16
    const unsigned short* __restrict__ Wb,   // [512][512] bf16 (OUT x IN)
    const unsigned short* __restrict__ W2b,  // [512][512] bf16
    const float* __restrict__ bias,          // [512]
    float* __restrict__ out)                 // [T][512] fp32
{
    __shared__ union {
        struct {
            unsigned short XS[64 * 64];   // 8KB
            unsigned short SS[64 * 64];   // 8KB
            unsigned short W [128 * 64];  // 16KB
            unsigned short W2[128 * 64];  // 16KB
        } stg;                            // 48KB
        float tr[64 * 132];               // out-transpose buffer (33.8KB)
    } u;
    const int tid  = threadIdx.x;
    const int lane = tid & 63;
    const int w    = tid >> 6;
    // XCD-chunked swizzle: 1024 blocks, 128 per XCD; 4 bn-siblings adjacent.
    const int tile = (blockIdx.x & 7) * 128 + (blockIdx.x >> 3);
    const int bm   = tile >> 2;   // 0..255 (64-token blocks)
    const int bn   = tile & 3;    // 0..3  (128-output blocks)

    const int srow  = lane >> 3;
    const int lslot = (lane & 7) ^ srow;
    const int fr    = lane & 15;
    const int fs    = lane >> 4;

    f32x4 a1[2][4] = {};
    f32x4 a2[2][4] = {};

    const size_t aBase = (size_t)bm * 64 * DIM;
    const size_t bBase = (size_t)bn * 128 * DIM;

    for (int kb = 0; kb < DIM; kb += 64) {
        // A tiles: 64x64 bf16 = 8KB = 2 wave-issues each (8 rows per issue)
#pragma unroll
        for (int q = 0; q < 2; ++q) {
            int rowb = (w * 2 + q) * 8;
            int row  = rowb + srow;
            size_t ga = aBase + (size_t)row * DIM + kb + lslot * 8;
            __builtin_amdgcn_global_load_lds(
                (__attribute__((address_space(1))) void*)(xs + ga),
                (__attribute__((address_space(3))) void*)(u.stg.XS + rowb * 64), 16, 0, 0);
            __builtin_amdgcn_global_load_lds(
                (__attribute__((address_space(1))) void*)(ss + ga),
                (__attribute__((address_space(3))) void*)(u.stg.SS + rowb * 64), 16, 0, 0);
        }
        // B tiles: 128x64 bf16 = 16KB = 4 wave-issues each
#pragma unroll
        for (int q = 0; q < 4; ++q) {
            int rowb = (w * 4 + q) * 8;
            int row  = rowb + srow;
            size_t gb = bBase + (size_t)row * DIM + kb + lslot * 8;
            __builtin_amdgcn_global_load_lds(
                (__attribute__((address_space(1))) void*)(Wb + gb),
                (__attribute__((address_space(3))) void*)(u.stg.W + rowb * 64), 16, 0, 0);
            __builtin_amdgcn_global_load_lds(
                (__attribute__((address_space(1))) void*)(W2b + gb),
                (__attribute__((address_space(3))) void*)(u.stg.W2 + rowb * 64), 16, 0, 0);
        }
        __syncthreads();
#pragma unroll
        for (int kk = 0; kk < 64; kk += 32) {
            bf16x8 axs[2], ass[2], bw[4], bw2[4];
#pragma unroll
            for (int mi = 0; mi < 2; ++mi) {
                int row = (w >> 1) * 32 + mi * 16 + fr;
                int ps  = ((kk >> 3) + fs) ^ (fr & 7);
                axs[mi] = *(const bf16x8*)(u.stg.XS + row * 64 + ps * 8);
                ass[mi] = *(const bf16x8*)(u.stg.SS + row * 64 + ps * 8);
            }
#pragma unroll
            for (int ni = 0; ni < 4; ++ni) {
                int row = (w & 1) * 64 + ni * 16 + fr;
                int ps  = ((kk >> 3) + fs) ^ (fr & 7);
                bw[ni]  = *(const bf16x8*)(u.stg.W  + row * 64 + ps * 8);
                bw2[ni] = *(const bf16x8*)(u.stg.W2 + row * 64 + ps * 8);
            }
#pragma unroll
            for (int mi = 0; mi < 2; ++mi)
#pragma unroll
                for (int ni = 0; ni < 4; ++ni) {
                    a1[mi][ni] = __builtin_amdgcn_mfma_f32_16x16x32_bf16(
                        axs[mi], bw[ni], a1[mi][ni], 0, 0, 0);
                    a2[mi][ni] = __builtin_amdgcn_mfma_f32_16x16x32_bf16(
                        ass[mi], bw2[ni], a2[mi][ni], 0, 0, 0);
                }
        }
        __syncthreads();
    }

    // epilogue: demod+bias into padded LDS [64][132], then float4 stores
#pragma unroll
    for (int ni = 0; ni < 4; ++ni) {
        int col = (w & 1) * 64 + ni * 16 + fr;
        float bo = bias[bn * 128 + col];
#pragma unroll
        for (int mi = 0; mi < 2; ++mi) {
#pragma unroll
            for (int j = 0; j < 4; ++j) {
                int row = (w >> 1) * 32 + mi * 16 + fs * 4 + j;
                float d = rsqrtf(a2[mi][ni][j] + 1e-8f);
                u.tr[row * 132 + col] = a1[mi][ni][j] * d + bo;
            }
        }
    }
    __syncthreads();
    {
        int r  = tid >> 2;
        int c0 = (tid & 3) * 32;
        size_t ob = ((size_t)bm * 64 + r) * DIM + bn * 128 + c0;
#pragma unroll
        for (int k = 0; k < 8; ++k)
            *(f32x4*)(out + ob + 4 * k) = *(const f32x4*)(u.tr + r * 132 + c0 + 4 * k);
    }
}

extern "C" void kernel_launch(void* const* d_in, const int* in_sizes, int n_in,
                              void* d_out, int out_size, void* d_ws, size_t ws_size,
                              hipStream_t stream) {
    const float* x      = (const float*)d_in[0];
    const float* mod    = (const float*)d_in[1];
    const float* weight = (const float*)d_in[2];
    const float* bias   = (const float*)d_in[3];
    const float* mod_w  = (const float*)d_in[4];
    const float* mod_b  = (const float*)d_in[5];
    float* out = (float*)d_out;

    char* ws = (char*)d_ws;
    unsigned short* modb = (unsigned short*)(ws);
    unsigned short* xs   = (unsigned short*)(ws + (size_t)16777216);
    unsigned short* ssb  = (unsigned short*)(ws + (size_t)2 * 16777216);
    unsigned short* Wb   = (unsigned short*)(ws + (size_t)3 * 16777216);
    unsigned short* W2b  = (unsigned short*)(ws + (size_t)3 * 16777216 + 524288);
    unsigned short* mwb  = (unsigned short*)(ws + (size_t)3 * 16777216 + 2 * 524288);

    hipLaunchKernelGGL(k0_convert, dim3(2048), dim3(256), 0, stream,
                       mod, weight, mod_w, modb, Wb, W2b, mwb);
    hipLaunchKernelGGL(k1_style, dim3(512), dim3(256), 0, stream,
                       modb, mwb, x, mod_b, xs, ssb);
    hipLaunchKernelGGL(k2_main, dim3(1024), dim3(256), 0, stream,
                       xs, ssb, Wb, W2b, bias, out);
}

// Round 4
// 54.788 us; speedup vs baseline: 1.7047x; 1.7047x over previous
//
#include <hip/hip_runtime.h>
#include <hip/hip_bf16.h>

// ModulatedLinear: B=4, S=4096, IN=OUT=MOD=512
// out[t,o] = demod[t,o] * sum_i W[o,i]*s[t,i]*x[t,i] + bias[o]
//   s[t,i]    = sum_m mod[t,m]*mod_w[i,m] + mod_b[i]
//   demod[t,o]= rsqrt(sum_i (W[o,i]*s[t,i])^2 + 1e-8)
//
// bf16 MFMA pipeline (round-2 structure, measured 0 LDS conflicts):
//  K0: fp32->bf16 converts
//  K1: s = modb @ mod_wb^T; LDS-transpose epilogue -> xs, ss   (launch_bounds(256,2))
//  K2: dual GEMM 128x128 tile + XCD-chunked swizzle (NEW, isolated change)

#define T_TOK 16384
#define DIM 512

typedef __attribute__((ext_vector_type(4))) float f32x4;
typedef __attribute__((ext_vector_type(8))) short bf16x8;

static __device__ __forceinline__ unsigned short f2bf(float f) {
    union { float f; unsigned int u; } v; v.f = f;
    unsigned int u = v.u;
    u += 0x7fffu + ((u >> 16) & 1u);   // RNE
    return (unsigned short)(u >> 16);
}
static __device__ __forceinline__ float bf2f(unsigned short h) {
    union { unsigned int u; float f; } v; v.u = ((unsigned int)h) << 16;
    return v.f;
}

// ---------------- K0: converts ----------------
__global__ __launch_bounds__(256) void k0_convert(
    const float* __restrict__ mod, const float* __restrict__ weight,
    const float* __restrict__ mod_w,
    unsigned short* __restrict__ modb, unsigned short* __restrict__ Wb,
    unsigned short* __restrict__ W2b, unsigned short* __restrict__ mwb)
{
    const int NV_MOD = (T_TOK * DIM) / 4;
    const int NV_W   = (DIM * DIM) / 4;
    int idx = blockIdx.x * blockDim.x + threadIdx.x;
    int stride = gridDim.x * blockDim.x;
    for (int i = idx; i < NV_MOD; i += stride) {
        f32x4 v = ((const f32x4*)mod)[i];
        ushort4 o; o.x = f2bf(v[0]); o.y = f2bf(v[1]); o.z = f2bf(v[2]); o.w = f2bf(v[3]);
        ((ushort4*)modb)[i] = o;
    }
    for (int i = idx; i < NV_W; i += stride) {
        f32x4 v = ((const f32x4*)weight)[i];
        ushort4 o;  o.x = f2bf(v[0]); o.y = f2bf(v[1]); o.z = f2bf(v[2]); o.w = f2bf(v[3]);
        ((ushort4*)Wb)[i] = o;
        ushort4 o2; o2.x = f2bf(v[0]*v[0]); o2.y = f2bf(v[1]*v[1]);
                    o2.z = f2bf(v[2]*v[2]); o2.w = f2bf(v[3]*v[3]);
        ((ushort4*)W2b)[i] = o2;
        f32x4 m = ((const f32x4*)mod_w)[i];
        ushort4 o3; o3.x = f2bf(m[0]); o3.y = f2bf(m[1]); o3.z = f2bf(m[2]); o3.w = f2bf(m[3]);
        ((ushort4*)mwb)[i] = o3;
    }
}

// LDS tiles: [rows][64] bf16, physical 16B-slot = logical ^ (row & 7).
// global_load_lds writes wave-uniform-base + lane*16, so the GLOBAL source
// address carries the swizzle (both-sides-or-neither).

// ---------------- K1: s-GEMM + LDS-transpose epilogue ----------------
__global__ __launch_bounds__(256, 2) void k1_style(
    const unsigned short* __restrict__ modb,   // [T][512] bf16
    const unsigned short* __restrict__ mwb,    // [512][512] bf16 (IN x MOD)
    const float* __restrict__ x,               // [T][512] fp32
    const float* __restrict__ mod_b,           // [512]
    unsigned short* __restrict__ xs,           // [T][512] bf16 out
    unsigned short* __restrict__ ss)           // [T][512] bf16 out
{
    __shared__ union {
        struct { unsigned short A[128 * 64]; unsigned short B[128 * 64]; } stg;
        unsigned short str[128 * 144];   // padded s-transpose buffer (36.9KB)
    } u;
    const int tid  = threadIdx.x;
    const int lane = tid & 63;
    const int w    = tid >> 6;
    const int wr   = w >> 1, wc = w & 1;
    const int nbn  = DIM / 128;             // 4
    const int bm   = blockIdx.x / nbn;
    const int bn   = blockIdx.x % nbn;

    const int srow  = lane >> 3;
    const int lslot = (lane & 7) ^ srow;
    const int fr    = lane & 15;
    const int fs    = lane >> 4;

    f32x4 acc[4][4] = {};

    const size_t aBase = (size_t)bm * 128 * DIM;
    const size_t bBase = (size_t)bn * 128 * DIM;

    for (int kb = 0; kb < DIM; kb += 64) {
#pragma unroll
        for (int q = 0; q < 4; ++q) {
            int row = w * 32 + q * 8 + srow;
            const unsigned short* ga = modb + aBase + (size_t)row * DIM + kb + lslot * 8;
            const unsigned short* gb = mwb  + bBase + (size_t)row * DIM + kb + lslot * 8;
            __builtin_amdgcn_global_load_lds(
                (__attribute__((address_space(1))) void*)ga,
                (__attribute__((address_space(3))) void*)(u.stg.A + w * 2048 + q * 512), 16, 0, 0);
            __builtin_amdgcn_global_load_lds(
                (__attribute__((address_space(1))) void*)gb,
                (__attribute__((address_space(3))) void*)(u.stg.B + w * 2048 + q * 512), 16, 0, 0);
        }
        __syncthreads();
#pragma unroll
        for (int kk = 0; kk < 64; kk += 32) {
            bf16x8 af[4], bfv[4];
#pragma unroll
            for (int mi = 0; mi < 4; ++mi) {
                int row = wr * 64 + mi * 16 + fr;
                int ps  = ((kk >> 3) + fs) ^ (fr & 7);
                af[mi] = *(const bf16x8*)(u.stg.A + row * 64 + ps * 8);
            }
#pragma unroll
            for (int ni = 0; ni < 4; ++ni) {
                int row = wc * 64 + ni * 16 + fr;
                int ps  = ((kk >> 3) + fs) ^ (fr & 7);
                bfv[ni] = *(const bf16x8*)(u.stg.B + row * 64 + ps * 8);
            }
#pragma unroll
            for (int mi = 0; mi < 4; ++mi)
#pragma unroll
                for (int ni = 0; ni < 4; ++ni)
                    acc[mi][ni] = __builtin_amdgcn_mfma_f32_16x16x32_bf16(
                        af[mi], bfv[ni], acc[mi][ni], 0, 0, 0);
        }
        __syncthreads();
    }

    // scatter s = acc + mod_b as bf16 into padded LDS [128][144]
#pragma unroll
    for (int ni = 0; ni < 4; ++ni) {
        int col = wc * 64 + ni * 16 + fr;
        float mb = mod_b[bn * 128 + col];
#pragma unroll
        for (int mi = 0; mi < 4; ++mi) {
#pragma unroll
            for (int j = 0; j < 4; ++j) {
                int row = wr * 64 + mi * 16 + fs * 4 + j;
                u.str[row * 144 + col] = f2bf(acc[mi][ni][j] + mb);
            }
        }
    }
    __syncthreads();
    // coalesced: read s rows, load x float4, write xs/ss ushort8
#pragma unroll
    for (int q = 0; q < 8; ++q) {
        int row = w * 32 + q * 4 + (lane >> 4);
        int c8  = (lane & 15) * 8;
        bf16x8 s8 = *(const bf16x8*)(u.str + row * 144 + c8);
        size_t off = ((size_t)bm * 128 + row) * DIM + bn * 128 + c8;
        f32x4 x0 = *(const f32x4*)(x + off);
        f32x4 x1 = *(const f32x4*)(x + off + 4);
        bf16x8 xsv, ssv;
#pragma unroll
        for (int e = 0; e < 8; ++e) {
            float sf = bf2f((unsigned short)s8[e]);
            float xv = (e < 4) ? x0[e] : x1[e - 4];
            xsv[e] = (short)f2bf(xv * sf);
            ssv[e] = (short)f2bf(sf * sf);
        }
        *(bf16x8*)(xs + off) = xsv;
        *(bf16x8*)(ss + off) = ssv;
    }
}

// ---------------- K2: dual GEMM 128x128 + XCD swizzle ----------------
__global__ __launch_bounds__(256, 2) void k2_main(
    const unsigned short* __restrict__ xs,   // [T][512] bf16
    const unsigned short* __restrict__ ss,   // [T][512] bf16
    const unsigned short* __restrict__ Wb,   // [512][512] bf16 (OUT x IN)
    const unsigned short* __restrict__ W2b,  // [512][512] bf16
    const float* __restrict__ bias,          // [512]
    float* __restrict__ out)                 // [T][512] fp32
{
    __shared__ unsigned short lXS[128 * 64];
    __shared__ unsigned short lSS[128 * 64];
    __shared__ unsigned short lW [128 * 64];
    __shared__ unsigned short lW2[128 * 64];
    const int tid  = threadIdx.x;
    const int lane = tid & 63;
    const int w    = tid >> 6;
    const int wr   = w >> 1, wc = w & 1;
    // XCD-chunked bijective swizzle (512 blocks, 64/XCD): the 4 bn-siblings of
    // consecutive bm's land on one XCD -> xs/ss panels hit in that XCD's L2.
    const int tile = (blockIdx.x & 7) * 64 + (blockIdx.x >> 3);
    const int bm   = tile >> 2;
    const int bn   = tile & 3;

    const int srow  = lane >> 3;
    const int lslot = (lane & 7) ^ srow;
    const int fr    = lane & 15;
    const int fs    = lane >> 4;

    f32x4 a1[4][4] = {};
    f32x4 a2[4][4] = {};

    const size_t aBase = (size_t)bm * 128 * DIM;
    const size_t bBase = (size_t)bn * 128 * DIM;

    for (int kb = 0; kb < DIM; kb += 64) {
#pragma unroll
        for (int q = 0; q < 4; ++q) {
            int row = w * 32 + q * 8 + srow;
            size_t goffA = aBase + (size_t)row * DIM + kb + lslot * 8;
            size_t goffB = bBase + (size_t)row * DIM + kb + lslot * 8;
            unsigned ldso = w * 2048 + q * 512;
            __builtin_amdgcn_global_load_lds(
                (__attribute__((address_space(1))) void*)(xs + goffA),
                (__attribute__((address_space(3))) void*)(lXS + ldso), 16, 0, 0);
            __builtin_amdgcn_global_load_lds(
                (__attribute__((address_space(1))) void*)(ss + goffA),
                (__attribute__((address_space(3))) void*)(lSS + ldso), 16, 0, 0);
            __builtin_amdgcn_global_load_lds(
                (__attribute__((address_space(1))) void*)(Wb + goffB),
                (__attribute__((address_space(3))) void*)(lW + ldso), 16, 0, 0);
            __builtin_amdgcn_global_load_lds(
                (__attribute__((address_space(1))) void*)(W2b + goffB),
                (__attribute__((address_space(3))) void*)(lW2 + ldso), 16, 0, 0);
        }
        __syncthreads();
#pragma unroll
        for (int kk = 0; kk < 64; kk += 32) {
            bf16x8 axs[4], ass[4], bw[4], bw2[4];
#pragma unroll
            for (int mi = 0; mi < 4; ++mi) {
                int row = wr * 64 + mi * 16 + fr;
                int ps  = ((kk >> 3) + fs) ^ (fr & 7);
                axs[mi] = *(const bf16x8*)(lXS + row * 64 + ps * 8);
                ass[mi] = *(const bf16x8*)(lSS + row * 64 + ps * 8);
            }
#pragma unroll
            for (int ni = 0; ni < 4; ++ni) {
                int row = wc * 64 + ni * 16 + fr;
                int ps  = ((kk >> 3) + fs) ^ (fr & 7);
                bw[ni]  = *(const bf16x8*)(lW  + row * 64 + ps * 8);
                bw2[ni] = *(const bf16x8*)(lW2 + row * 64 + ps * 8);
            }
#pragma unroll
            for (int mi = 0; mi < 4; ++mi)
#pragma unroll
                for (int ni = 0; ni < 4; ++ni) {
                    a1[mi][ni] = __builtin_amdgcn_mfma_f32_16x16x32_bf16(
                        axs[mi], bw[ni], a1[mi][ni], 0, 0, 0);
                    a2[mi][ni] = __builtin_amdgcn_mfma_f32_16x16x32_bf16(
                        ass[mi], bw2[ni], a2[mi][ni], 0, 0, 0);
                }
        }
        __syncthreads();
    }

    // epilogue: out = a1 * rsqrt(a2 + eps) + bias (direct scalar stores)
#pragma unroll
    for (int ni = 0; ni < 4; ++ni) {
        int o = bn * 128 + wc * 64 + ni * 16 + fr;
        float bo = bias[o];
#pragma unroll
        for (int mi = 0; mi < 4; ++mi) {
#pragma unroll
            for (int j = 0; j < 4; ++j) {
                size_t t = (size_t)bm * 128 + wr * 64 + mi * 16 + fs * 4 + j;
                float d = rsqrtf(a2[mi][ni][j] + 1e-8f);
                out[t * DIM + o] = a1[mi][ni][j] * d + bo;
            }
        }
    }
}

extern "C" void kernel_launch(void* const* d_in, const int* in_sizes, int n_in,
                              void* d_out, int out_size, void* d_ws, size_t ws_size,
                              hipStream_t stream) {
    const float* x      = (const float*)d_in[0];
    const float* mod    = (const float*)d_in[1];
    const float* weight = (const float*)d_in[2];
    const float* bias   = (const float*)d_in[3];
    const float* mod_w  = (const float*)d_in[4];
    const float* mod_b  = (const float*)d_in[5];
    float* out = (float*)d_out;

    char* ws = (char*)d_ws;
    unsigned short* modb = (unsigned short*)(ws);
    unsigned short* xs   = (unsigned short*)(ws + (size_t)16777216);
    unsigned short* ssb  = (unsigned short*)(ws + (size_t)2 * 16777216);
    unsigned short* Wb   = (unsigned short*)(ws + (size_t)3 * 16777216);
    unsigned short* W2b  = (unsigned short*)(ws + (size_t)3 * 16777216 + 524288);
    unsigned short* mwb  = (unsigned short*)(ws + (size_t)3 * 16777216 + 2 * 524288);

    hipLaunchKernelGGL(k0_convert, dim3(2048), dim3(256), 0, stream,
                       mod, weight, mod_w, modb, Wb, W2b, mwb);
    hipLaunchKernelGGL(k1_style, dim3(512), dim3(256), 0, stream,
                       modb, mwb, x, mod_b, xs, ssb);
    hipLaunchKernelGGL(k2_main, dim3(512), dim3(256), 0, stream,
                       xs, ssb, Wb, W2b, bias, out);
}